// Round 21
// baseline (108.531 us; speedup 1.0000x reference)
//
#include <hip/hip_runtime.h>
#include <hip/hip_bf16.h>

#define BCH 32   // B*C heads
#define NN  2048
#define DD  64   // F = H = O

typedef __attribute__((ext_vector_type(8)))  __bf16 bf16x8;
typedef __attribute__((ext_vector_type(4)))  __bf16 bf16x4;
typedef __attribute__((ext_vector_type(4)))  float  f32x4;
typedef __attribute__((ext_vector_type(16))) float  f32x16;
typedef __attribute__((ext_vector_type(2)))  int    i32x2;
typedef __attribute__((ext_vector_type(4)))  int    i32x4;
typedef __attribute__((ext_vector_type(2)))  unsigned int u32x2;

__device__ inline f32x4 mfma16(bf16x8 a, bf16x8 b, f32x4 c) {
    return __builtin_amdgcn_mfma_f32_16x16x32_bf16(a, b, c, 0, 0, 0);
}
__device__ inline f32x16 mfma32(bf16x8 a, bf16x8 b, f32x16 c) {
    return __builtin_amdgcn_mfma_f32_32x32x16_bf16(a, b, c, 0, 0, 0);
}
// permlane32_swap BUILTIN (validated round 9)
__device__ inline void plswap(int& a, int& b) {
    u32x2 r = __builtin_amdgcn_permlane32_swap((unsigned)a, (unsigned)b, false, false);
    a = (int)r[0];
    b = (int)r[1];
}

// ---------------------------------------------------------------------------
// Kernel 1 (unchanged, validated rounds 15-18): fragment-linear outputs
//   E1F [bc][nt64][c][r], E2F [bc][kt64][c][r], VTF [bc][kt64][d][o]
// ---------------------------------------------------------------------------
__global__ __launch_bounds__(256) void prep_kernel(
    const float* __restrict__ x,
    const float* __restrict__ W1, const float* __restrict__ b1,
    const float* __restrict__ W2, const float* __restrict__ b2,
    const float* __restrict__ W3,
    __bf16* __restrict__ e1f, __bf16* __restrict__ e2f, __bf16* __restrict__ vtf)
{
    const int t   = threadIdx.x;
    const int blk = blockIdx.x;
    const int bc  = blk >> 5, st = blk & 31;
    const long grow = (long)bc * NN + st * 64;
    const int w = t >> 6, l = t & 63, lg = l >> 4, li = l & 15;

    bf16x8 a[4][2];
    #pragma unroll
    for (int nb = 0; nb < 4; ++nb)
        #pragma unroll
        for (int kk = 0; kk < 2; ++kk) {
            const float* p = x + (grow + nb * 16 + li) * DD + kk * 32 + lg * 8;
            f32x4 v0 = *(const f32x4*)p, v1 = *(const f32x4*)(p + 4);
            #pragma unroll
            for (int j = 0; j < 4; ++j) {
                a[nb][kk][j]     = (__bf16)v0[j];
                a[nb][kk][4 + j] = (__bf16)v1[j];
            }
        }

    bf16x8 wf1[2], wf2[2], wf3[2];
    #pragma unroll
    for (int kk = 0; kk < 2; ++kk) {
        const float* p1 = W1 + (w * 16 + li) * DD + kk * 32 + lg * 8;
        const float* p2 = W2 + (w * 16 + li) * DD + kk * 32 + lg * 8;
        const float* p3 = W3 + (w * 16 + li) * DD + kk * 32 + lg * 8;
        f32x4 u0 = *(const f32x4*)p1, u1 = *(const f32x4*)(p1 + 4);
        f32x4 v0 = *(const f32x4*)p2, v1 = *(const f32x4*)(p2 + 4);
        f32x4 t0 = *(const f32x4*)p3, t1 = *(const f32x4*)(p3 + 4);
        #pragma unroll
        for (int j = 0; j < 4; ++j) {
            wf1[kk][j] = (__bf16)u0[j]; wf1[kk][4 + j] = (__bf16)u1[j];
            wf2[kk][j] = (__bf16)v0[j]; wf2[kk][4 + j] = (__bf16)v1[j];
            wf3[kk][j] = (__bf16)t0[j]; wf3[kk][4 + j] = (__bf16)t1[j];
        }
    }
    const f32x4 bq1 = *(const f32x4*)(b1 + w * 16 + lg * 4);
    const f32x4 bq2 = *(const f32x4*)(b2 + w * 16 + lg * 4);

    const size_t tbase = (size_t)(bc * 32 + st) * 4096;

    #pragma unroll
    for (int nb = 0; nb < 4; ++nb) {
        f32x4 acc1 = {0.f,0.f,0.f,0.f}, acc2 = {0.f,0.f,0.f,0.f}, acc3 = {0.f,0.f,0.f,0.f};
        #pragma unroll
        for (int kk = 0; kk < 2; ++kk) {
            acc1 = mfma16(wf1[kk], a[nb][kk], acc1);   // D[h][n]
            acc2 = mfma16(wf2[kk], a[nb][kk], acc2);   // D[h][n]
            acc3 = mfma16(a[nb][kk], wf3[kk], acc3);   // D[n][o]
        }
        bf16x4 q1, q2, q3;
        #pragma unroll
        for (int r = 0; r < 4; ++r) {
            q1[r] = (__bf16)(acc1[r] + bq1[r]);
            q2[r] = (__bf16)(acc2[r] + bq2[r]);
            q3[r] = (__bf16)acc3[r];
        }
        *(bf16x4*)&e1f[tbase + (w * 2 + (lg >> 1)) * 512 + (nb * 16 + li) * 8 + (lg & 1) * 4] = q1;
        *(bf16x4*)&e2f[tbase + (w * 2 + (lg >> 1)) * 512 + (nb * 16 + li) * 8 + (lg & 1) * 4] = q2;
        *(bf16x4*)&vtf[tbase + (nb * 2 + (lg >> 1)) * 512 + (w * 16 + li) * 8 + (lg & 1) * 4] = q3;
    }
}

// ---------------------------------------------------------------------------
// Kernel 2 v10: LDS-free barrier-free K-loop + kt-SPLIT across waves.
// grid 1024 (XCD-grouped), block 256 = 4 waves = 2 wm (m-half) x 2 kp
// (kt-parity). Each wave: 64 n x 32 m-half x 16 kts (kt = 2i+kp).
// 4096 waves total (2x round 18) at UNCHANGED bytes/MFMA -> pipes overlap.
// Epilogue: 2-stage LDS combine (kp pairs, then wm pair), 32KB scratch.
// ---------------------------------------------------------------------------
__global__ __launch_bounds__(256, 3) void fused_kernel(
    const __bf16* __restrict__ e1f, const __bf16* __restrict__ e2f,
    const __bf16* __restrict__ vtf, const float* __restrict__ b3,
    float* __restrict__ out)
{
    __shared__ float scratch[8192];      // 32 KB: two 16KB partial regions

    const int t   = threadIdx.x;
    const int bid = blockIdx.x;
    const int x8 = bid & 7, jj = bid >> 3;
    const int bc = x8 * 4 + (jj >> 5), nt = jj & 31;

    const int w = t >> 6, l = t & 63;
    const int wm = w & 1, kp = w >> 1;
    const int l31 = l & 31, hi5 = l >> 5;
    const int nbase = nt * 64;

    const float bv0 = b3[l31], bv1 = b3[32 + l31];

    // e1 fragments for both nb (validated round 18)
    bf16x8 e1v[2][4];
    #pragma unroll
    for (int nb = 0; nb < 2; ++nb) {
        const __bf16* p = e1f + ((size_t)bc * 32 + nt) * 4096 + hi5 * 512 + (nb * 32 + l31) * 8;
        #pragma unroll
        for (int kk = 0; kk < 4; ++kk)
            e1v[nb][kk] = *(const bf16x8*)(p + kk * 1024);
    }

    f32x16 fz;
    #pragma unroll
    for (int i = 0; i < 16; ++i) fz[i] = 0.f;
    f32x16 hacc[2][2];   // [nb][fb], partial over this wave's (wm, kp) share
    #pragma unroll
    for (int nb = 0; nb < 2; ++nb)
        #pragma unroll
        for (int fb = 0; fb < 2; ++fb)
            #pragma unroll
            for (int i = 0; i < 16; ++i) hacc[nb][fb][i] = 0.f;

    const __bf16* E2 = e2f + (size_t)bc * 131072 + hi5 * 512 + (wm * 32 + l31) * 8;
    const __bf16* VT = vtf + (size_t)bc * 131072 + (wm * 4 + hi5) * 512 + l31 * 8;

    auto loadEF = [&](int kt, bf16x8 (&ef)[4]) {
        const __bf16* p = E2 + (size_t)kt * 4096;
        #pragma unroll
        for (int kk = 0; kk < 4; ++kk)
            ef[kk] = *(const bf16x8*)(p + kk * 1024);
    };
    auto loadVF = [&](int kt, bf16x8 (&vf)[4]) {
        const __bf16* p = VT + (size_t)kt * 4096;
        #pragma unroll
        for (int kk2 = 0; kk2 < 2; ++kk2) {
            vf[kk2 * 2 + 0] = *(const bf16x8*)(p + kk2 * 1024);
            vf[kk2 * 2 + 1] = *(const bf16x8*)(p + kk2 * 1024 + 256);
        }
    };
    // two independent S chains (one per nb), ef shared (validated round 18)
    auto computeS = [&](bf16x8 (&ef)[4], f32x16 (&sT)[2]) {
        sT[0] = mfma32(ef[0], e1v[0][0], fz);
        sT[1] = mfma32(ef[0], e1v[1][0], fz);
        #pragma unroll
        for (int kk = 1; kk < 4; ++kk) {
            sT[0] = mfma32(ef[kk], e1v[0][kk], sT[0]);
            sT[1] = mfma32(ef[kk], e1v[1][kk], sT[1]);
        }
    };
    auto packQ = [&](const f32x16 (&sT)[2], i32x2 (&Q)[2][4]) {
        #pragma unroll
        for (int nb = 0; nb < 2; ++nb)
            #pragma unroll
            for (int g = 0; g < 4; ++g) {
                bf16x4 q0;
                #pragma unroll
                for (int r = 0; r < 4; ++r)
                    q0[r] = (__bf16)fmaxf(sT[nb][4 * g + r], 0.f);
                Q[nb][g] = __builtin_bit_cast(i32x2, q0);
            }
    };
    auto doPV = [&](i32x2 (&Q)[2][4], bf16x8 (&vf)[4]) {
        #pragma unroll
        for (int kk2 = 0; kk2 < 2; ++kk2)
            #pragma unroll
            for (int nb = 0; nb < 2; ++nb) {
                int a0 = Q[nb][2 * kk2][0],     a1 = Q[nb][2 * kk2][1];
                int b0 = Q[nb][2 * kk2 + 1][0], b1 = Q[nb][2 * kk2 + 1][1];
                plswap(a0, b0);
                plswap(a1, b1);
                i32x4 pfi = { a0, a1, b0, b1 };
                bf16x8 pf = __builtin_bit_cast(bf16x8, pfi);
                hacc[nb][0] = mfma32(pf, vf[kk2 * 2 + 0], hacc[nb][0]);
                hacc[nb][1] = mfma32(pf, vf[kk2 * 2 + 1], hacc[nb][1]);
            }
    };

    bf16x8 efA[4], vfA[4], efB[4], vfB[4];
    i32x2 Qa[2][4], Qb[2][4];
    f32x16 sT[2];

    // this wave's kts: kt = 2*i + kp, i = 0..15
    loadEF(kp, efA); loadVF(kp, vfA);
    for (int j = 0; j < 16; j += 2) {
        const int ktB = 2 * (j + 1) + kp;
        loadEF(ktB, efB); loadVF(ktB, vfB);
        computeS(efA, sT);
        packQ(sT, Qa);
        doPV(Qa, vfA);
        if (j + 2 < 16) {
            const int ktA = 2 * (j + 2) + kp;
            loadEF(ktA, efA); loadVF(ktA, vfA);
        }
        computeS(efB, sT);
        packQ(sT, Qb);
        doPV(Qb, vfB);
    }

    // ---- epilogue: 2-stage combine (kp pairs -> wm pair), then store ----
    // stage 1: kp==1 waves publish; kp==0 waves absorb
    if (kp == 1) {
        #pragma unroll
        for (int nb = 0; nb < 2; ++nb)
            #pragma unroll
            for (int q = 0; q < 8; ++q) {
                f32x4 v;
                #pragma unroll
                for (int r = 0; r < 4; ++r) {
                    const int idx = q * 4 + r;          // 0..31
                    v[r] = hacc[nb][idx >> 4][idx & 15];
                }
                *(f32x4*)&scratch[wm * 4096 + nb * 2048 + q * 256 + l * 4] = v;
            }
    }
    __syncthreads();
    if (kp == 0) {
        #pragma unroll
        for (int nb = 0; nb < 2; ++nb)
            #pragma unroll
            for (int q = 0; q < 8; ++q) {
                f32x4 v = *(const f32x4*)&scratch[wm * 4096 + nb * 2048 + q * 256 + l * 4];
                #pragma unroll
                for (int r = 0; r < 4; ++r) {
                    const int idx = q * 4 + r;
                    hacc[nb][idx >> 4][idx & 15] += v[r];
                }
            }
    }
    __syncthreads();
    // stage 2: (wm==1,kp==0) publishes; (wm==0,kp==0) absorbs + stores
    if (kp == 0 && wm == 1) {
        #pragma unroll
        for (int nb = 0; nb < 2; ++nb)
            #pragma unroll
            for (int q = 0; q < 8; ++q) {
                f32x4 v;
                #pragma unroll
                for (int r = 0; r < 4; ++r) {
                    const int idx = q * 4 + r;
                    v[r] = hacc[nb][idx >> 4][idx & 15];
                }
                *(f32x4*)&scratch[nb * 2048 + q * 256 + l * 4] = v;
            }
    }
    __syncthreads();
    if (kp == 0 && wm == 0) {
        #pragma unroll
        for (int nb = 0; nb < 2; ++nb)
            #pragma unroll
            for (int q = 0; q < 8; ++q) {
                f32x4 v = *(const f32x4*)&scratch[nb * 2048 + q * 256 + l * 4];
                #pragma unroll
                for (int r = 0; r < 4; ++r) {
                    const int idx = q * 4 + r;
                    hacc[nb][idx >> 4][idx & 15] += v[r];
                }
            }
        #pragma unroll
        for (int nb = 0; nb < 2; ++nb) {
            const size_t ob = ((size_t)bc * NN + nbase + nb * 32) * DD;
            #pragma unroll
            for (int reg = 0; reg < 16; ++reg) {
                const int n = (reg & 3) + 8 * (reg >> 2) + 4 * hi5;
                out[ob + (size_t)n * DD + l31]      = hacc[nb][0][reg] + bv0;
                out[ob + (size_t)n * DD + 32 + l31] = hacc[nb][1][reg] + bv1;
            }
        }
    }
}

extern "C" void kernel_launch(void* const* d_in, const int* in_sizes, int n_in,
                              void* d_out, int out_size, void* d_ws, size_t ws_size,
                              hipStream_t stream) {
    const float* x  = (const float*)d_in[0];
    const float* W1 = (const float*)d_in[1];
    const float* b1 = (const float*)d_in[2];
    const float* W2 = (const float*)d_in[3];
    const float* b2 = (const float*)d_in[4];
    const float* W3 = (const float*)d_in[5];
    const float* b3 = (const float*)d_in[6];
    float* out = (float*)d_out;

    __bf16* e1f = (__bf16*)d_ws;                      // 8 MB fragment-linear
    __bf16* e2f = e1f + (size_t)BCH * NN * DD;        // 8 MB fragment-linear
    __bf16* vtf = e2f + (size_t)BCH * NN * DD;        // 8 MB fragment-linear

    prep_kernel<<<dim3(1024), dim3(256), 0, stream>>>(x, W1, b1, W2, b2, W3, e1f, e2f, vtf);
    fused_kernel<<<dim3(1024), dim3(256), 0, stream>>>(e1f, e2f, vtf, b3, out);
}

// Round 22
// 59.472 us; speedup vs baseline: 1.8249x; 1.8249x over previous
//
#include <hip/hip_runtime.h>
#include <hip/hip_bf16.h>

#define BCH 32   // B*C heads
#define NN  2048
#define DD  64   // F = H = O

typedef __attribute__((ext_vector_type(8)))  __bf16 bf16x8;
typedef __attribute__((ext_vector_type(4)))  __bf16 bf16x4;
typedef __attribute__((ext_vector_type(4)))  float  f32x4;
typedef __attribute__((ext_vector_type(16))) float  f32x16;
typedef __attribute__((ext_vector_type(2)))  int    i32x2;
typedef __attribute__((ext_vector_type(4)))  int    i32x4;
typedef __attribute__((ext_vector_type(2)))  unsigned int u32x2;

__device__ inline f32x4 mfma16(bf16x8 a, bf16x8 b, f32x4 c) {
    return __builtin_amdgcn_mfma_f32_16x16x32_bf16(a, b, c, 0, 0, 0);
}
__device__ inline f32x16 mfma32(bf16x8 a, bf16x8 b, f32x16 c) {
    return __builtin_amdgcn_mfma_f32_32x32x16_bf16(a, b, c, 0, 0, 0);
}
// permlane32_swap BUILTIN (validated round 9)
__device__ inline void plswap(int& a, int& b) {
    u32x2 r = __builtin_amdgcn_permlane32_swap((unsigned)a, (unsigned)b, false, false);
    a = (int)r[0];
    b = (int)r[1];
}

// ---------------------------------------------------------------------------
// Kernel 1 (unchanged, validated rounds 15-18): fragment-linear outputs
//   E1F [bc][nt64][c][r], E2F [bc][kt64][c][r], VTF [bc][kt64][d][o]
// ---------------------------------------------------------------------------
__global__ __launch_bounds__(256) void prep_kernel(
    const float* __restrict__ x,
    const float* __restrict__ W1, const float* __restrict__ b1,
    const float* __restrict__ W2, const float* __restrict__ b2,
    const float* __restrict__ W3,
    __bf16* __restrict__ e1f, __bf16* __restrict__ e2f, __bf16* __restrict__ vtf)
{
    const int t   = threadIdx.x;
    const int blk = blockIdx.x;
    const int bc  = blk >> 5, st = blk & 31;
    const long grow = (long)bc * NN + st * 64;
    const int w = t >> 6, l = t & 63, lg = l >> 4, li = l & 15;

    bf16x8 a[4][2];
    #pragma unroll
    for (int nb = 0; nb < 4; ++nb)
        #pragma unroll
        for (int kk = 0; kk < 2; ++kk) {
            const float* p = x + (grow + nb * 16 + li) * DD + kk * 32 + lg * 8;
            f32x4 v0 = *(const f32x4*)p, v1 = *(const f32x4*)(p + 4);
            #pragma unroll
            for (int j = 0; j < 4; ++j) {
                a[nb][kk][j]     = (__bf16)v0[j];
                a[nb][kk][4 + j] = (__bf16)v1[j];
            }
        }

    bf16x8 wf1[2], wf2[2], wf3[2];
    #pragma unroll
    for (int kk = 0; kk < 2; ++kk) {
        const float* p1 = W1 + (w * 16 + li) * DD + kk * 32 + lg * 8;
        const float* p2 = W2 + (w * 16 + li) * DD + kk * 32 + lg * 8;
        const float* p3 = W3 + (w * 16 + li) * DD + kk * 32 + lg * 8;
        f32x4 u0 = *(const f32x4*)p1, u1 = *(const f32x4*)(p1 + 4);
        f32x4 v0 = *(const f32x4*)p2, v1 = *(const f32x4*)(p2 + 4);
        f32x4 t0 = *(const f32x4*)p3, t1 = *(const f32x4*)(p3 + 4);
        #pragma unroll
        for (int j = 0; j < 4; ++j) {
            wf1[kk][j] = (__bf16)u0[j]; wf1[kk][4 + j] = (__bf16)u1[j];
            wf2[kk][j] = (__bf16)v0[j]; wf2[kk][4 + j] = (__bf16)v1[j];
            wf3[kk][j] = (__bf16)t0[j]; wf3[kk][4 + j] = (__bf16)t1[j];
        }
    }
    const f32x4 bq1 = *(const f32x4*)(b1 + w * 16 + lg * 4);
    const f32x4 bq2 = *(const f32x4*)(b2 + w * 16 + lg * 4);

    const size_t tbase = (size_t)(bc * 32 + st) * 4096;

    #pragma unroll
    for (int nb = 0; nb < 4; ++nb) {
        f32x4 acc1 = {0.f,0.f,0.f,0.f}, acc2 = {0.f,0.f,0.f,0.f}, acc3 = {0.f,0.f,0.f,0.f};
        #pragma unroll
        for (int kk = 0; kk < 2; ++kk) {
            acc1 = mfma16(wf1[kk], a[nb][kk], acc1);   // D[h][n]
            acc2 = mfma16(wf2[kk], a[nb][kk], acc2);   // D[h][n]
            acc3 = mfma16(a[nb][kk], wf3[kk], acc3);   // D[n][o]
        }
        bf16x4 q1, q2, q3;
        #pragma unroll
        for (int r = 0; r < 4; ++r) {
            q1[r] = (__bf16)(acc1[r] + bq1[r]);
            q2[r] = (__bf16)(acc2[r] + bq2[r]);
            q3[r] = (__bf16)acc3[r];
        }
        *(bf16x4*)&e1f[tbase + (w * 2 + (lg >> 1)) * 512 + (nb * 16 + li) * 8 + (lg & 1) * 4] = q1;
        *(bf16x4*)&e2f[tbase + (w * 2 + (lg >> 1)) * 512 + (nb * 16 + li) * 8 + (lg & 1) * 4] = q2;
        *(bf16x4*)&vtf[tbase + (nb * 2 + (lg >> 1)) * 512 + (w * 16 + li) * 8 + (lg & 1) * 4] = q3;
    }
}

// ---------------------------------------------------------------------------
// Kernel 2 v11: = round-18 v8 (best) with ONE change: computeS uses FOUR
// independent MFMA chains of depth 2 (was two chains of depth 4) to cover
// mfma32 dependent-issue latency. P = relu(sA+sB).
// ---------------------------------------------------------------------------
__global__ __launch_bounds__(128, 2) void fused_kernel(
    const __bf16* __restrict__ e1f, const __bf16* __restrict__ e2f,
    const __bf16* __restrict__ vtf, const float* __restrict__ b3,
    float* __restrict__ out)
{
    __shared__ float scratch[4096];      // epilogue m-half combine (16KB)

    const int t   = threadIdx.x;
    const int bid = blockIdx.x;
    const int x8 = bid & 7, jj = bid >> 3;          // jj in 0..127
    const int bc = x8 * 4 + (jj & 3), nt = jj >> 2;

    const int wm = t >> 6, l = t & 63;
    const int l31 = l & 31, hi5 = l >> 5;
    const int nbase = nt * 64;

    const float bv0 = b3[l31], bv1 = b3[32 + l31];

    // e1 fragments for both nb (shared-k layout), from fragment-linear E1F
    bf16x8 e1v[2][4];
    #pragma unroll
    for (int nb = 0; nb < 2; ++nb) {
        const __bf16* p = e1f + ((size_t)bc * 32 + nt) * 4096 + hi5 * 512 + (nb * 32 + l31) * 8;
        #pragma unroll
        for (int kk = 0; kk < 4; ++kk)
            e1v[nb][kk] = *(const bf16x8*)(p + kk * 1024);
    }

    f32x16 fz;
    #pragma unroll
    for (int i = 0; i < 16; ++i) fz[i] = 0.f;
    f32x16 hacc[2][2];   // [nb][fb]
    #pragma unroll
    for (int nb = 0; nb < 2; ++nb)
        #pragma unroll
        for (int fb = 0; fb < 2; ++fb)
            #pragma unroll
            for (int i = 0; i < 16; ++i) hacc[nb][fb][i] = 0.f;

    const __bf16* E2 = e2f + (size_t)bc * 131072 + hi5 * 512 + (wm * 32 + l31) * 8;
    const __bf16* VT = vtf + (size_t)bc * 131072 + (wm * 4 + hi5) * 512 + l31 * 8;

    auto loadEF = [&](int kt, bf16x8 (&ef)[4]) {
        const __bf16* p = E2 + (size_t)kt * 4096;
        #pragma unroll
        for (int kk = 0; kk < 4; ++kk)
            ef[kk] = *(const bf16x8*)(p + kk * 1024);
    };
    auto loadVF = [&](int kt, bf16x8 (&vf)[4]) {
        const __bf16* p = VT + (size_t)kt * 4096;
        #pragma unroll
        for (int kk2 = 0; kk2 < 2; ++kk2) {
            vf[kk2 * 2 + 0] = *(const bf16x8*)(p + kk2 * 1024);
            vf[kk2 * 2 + 1] = *(const bf16x8*)(p + kk2 * 1024 + 256);
        }
    };
    // FOUR independent S chains (2 nb x 2 k-halves), depth 2 each
    auto computeS = [&](bf16x8 (&ef)[4], f32x16 (&sT)[2]) {
        f32x16 sA0 = mfma32(ef[0], e1v[0][0], fz);
        f32x16 sB0 = mfma32(ef[1], e1v[0][1], fz);
        f32x16 sA1 = mfma32(ef[0], e1v[1][0], fz);
        f32x16 sB1 = mfma32(ef[1], e1v[1][1], fz);
        sA0 = mfma32(ef[2], e1v[0][2], sA0);
        sB0 = mfma32(ef[3], e1v[0][3], sB0);
        sA1 = mfma32(ef[2], e1v[1][2], sA1);
        sB1 = mfma32(ef[3], e1v[1][3], sB1);
        #pragma unroll
        for (int i = 0; i < 16; ++i) {
            sT[0][i] = sA0[i] + sB0[i];
            sT[1][i] = sA1[i] + sB1[i];
        }
    };
    auto packQ = [&](const f32x16 (&sT)[2], i32x2 (&Q)[2][4]) {
        #pragma unroll
        for (int nb = 0; nb < 2; ++nb)
            #pragma unroll
            for (int g = 0; g < 4; ++g) {
                bf16x4 q0;
                #pragma unroll
                for (int r = 0; r < 4; ++r)
                    q0[r] = (__bf16)fmaxf(sT[nb][4 * g + r], 0.f);
                Q[nb][g] = __builtin_bit_cast(i32x2, q0);
            }
    };
    auto doPV = [&](i32x2 (&Q)[2][4], bf16x8 (&vf)[4]) {
        #pragma unroll
        for (int kk2 = 0; kk2 < 2; ++kk2)
            #pragma unroll
            for (int nb = 0; nb < 2; ++nb) {
                int a0 = Q[nb][2 * kk2][0],     a1 = Q[nb][2 * kk2][1];
                int b0 = Q[nb][2 * kk2 + 1][0], b1 = Q[nb][2 * kk2 + 1][1];
                plswap(a0, b0);
                plswap(a1, b1);
                i32x4 pfi = { a0, a1, b0, b1 };
                bf16x8 pf = __builtin_bit_cast(bf16x8, pfi);
                hacc[nb][0] = mfma32(pf, vf[kk2 * 2 + 0], hacc[nb][0]);
                hacc[nb][1] = mfma32(pf, vf[kk2 * 2 + 1], hacc[nb][1]);
            }
    };

    bf16x8 efA[4], vfA[4], efB[4], vfB[4];
    i32x2 Qa[2][4], Qb[2][4];
    f32x16 sT[2];

    loadEF(0, efA); loadVF(0, vfA);
    for (int kt = 0; kt < 32; kt += 2) {
        loadEF(kt + 1, efB); loadVF(kt + 1, vfB);   // prefetch odd tile
        computeS(efA, sT);
        packQ(sT, Qa);
        doPV(Qa, vfA);
        if (kt + 2 < 32) { loadEF(kt + 2, efA); loadVF(kt + 2, vfA); }
        computeS(efB, sT);
        packQ(sT, Qb);
        doPV(Qb, vfB);
    }

    // ---- epilogue: combine m-halves via LDS, add b3, store fp32 ----
    if (wm == 1) {
        #pragma unroll
        for (int nb = 0; nb < 2; ++nb)
            #pragma unroll
            for (int q = 0; q < 8; ++q) {
                f32x4 v;
                #pragma unroll
                for (int r = 0; r < 4; ++r) {
                    const int idx = q * 4 + r;          // 0..31
                    v[r] = hacc[nb][idx >> 4][idx & 15];
                }
                *(f32x4*)&scratch[nb * 2048 + q * 256 + l * 4] = v;
            }
    }
    __syncthreads();
    if (wm == 0) {
        #pragma unroll
        for (int nb = 0; nb < 2; ++nb)
            #pragma unroll
            for (int q = 0; q < 8; ++q) {
                f32x4 v = *(const f32x4*)&scratch[nb * 2048 + q * 256 + l * 4];
                #pragma unroll
                for (int r = 0; r < 4; ++r) {
                    const int idx = q * 4 + r;
                    hacc[nb][idx >> 4][idx & 15] += v[r];
                }
            }
        #pragma unroll
        for (int nb = 0; nb < 2; ++nb) {
            const size_t ob = ((size_t)bc * NN + nbase + nb * 32) * DD;
            #pragma unroll
            for (int reg = 0; reg < 16; ++reg) {
                const int n = (reg & 3) + 8 * (reg >> 2) + 4 * hi5;
                out[ob + (size_t)n * DD + l31]      = hacc[nb][0][reg] + bv0;
                out[ob + (size_t)n * DD + 32 + l31] = hacc[nb][1][reg] + bv1;
            }
        }
    }
}

extern "C" void kernel_launch(void* const* d_in, const int* in_sizes, int n_in,
                              void* d_out, int out_size, void* d_ws, size_t ws_size,
                              hipStream_t stream) {
    const float* x  = (const float*)d_in[0];
    const float* W1 = (const float*)d_in[1];
    const float* b1 = (const float*)d_in[2];
    const float* W2 = (const float*)d_in[3];
    const float* b2 = (const float*)d_in[4];
    const float* W3 = (const float*)d_in[5];
    const float* b3 = (const float*)d_in[6];
    float* out = (float*)d_out;

    __bf16* e1f = (__bf16*)d_ws;                      // 8 MB fragment-linear
    __bf16* e2f = e1f + (size_t)BCH * NN * DD;        // 8 MB fragment-linear
    __bf16* vtf = e2f + (size_t)BCH * NN * DD;        // 8 MB fragment-linear

    prep_kernel<<<dim3(1024), dim3(256), 0, stream>>>(x, W1, b1, W2, b2, W3, e1f, e2f, vtf);
    fused_kernel<<<dim3(1024), dim3(128), 0, stream>>>(e1f, e2f, vtf, b3, out);
}

// Round 23
// 58.925 us; speedup vs baseline: 1.8418x; 1.0093x over previous
//
#include <hip/hip_runtime.h>
#include <hip/hip_bf16.h>

#define BCH 32   // B*C heads
#define NN  2048
#define DD  64   // F = H = O

typedef __attribute__((ext_vector_type(8)))  __bf16 bf16x8;
typedef __attribute__((ext_vector_type(4)))  __bf16 bf16x4;
typedef __attribute__((ext_vector_type(4)))  float  f32x4;
typedef __attribute__((ext_vector_type(16))) float  f32x16;
typedef __attribute__((ext_vector_type(2)))  int    i32x2;
typedef __attribute__((ext_vector_type(4)))  int    i32x4;
typedef __attribute__((ext_vector_type(2)))  unsigned int u32x2;

__device__ inline f32x4 mfma16(bf16x8 a, bf16x8 b, f32x4 c) {
    return __builtin_amdgcn_mfma_f32_16x16x32_bf16(a, b, c, 0, 0, 0);
}
__device__ inline f32x16 mfma32(bf16x8 a, bf16x8 b, f32x16 c) {
    return __builtin_amdgcn_mfma_f32_32x32x16_bf16(a, b, c, 0, 0, 0);
}
// permlane32_swap BUILTIN (validated round 9)
__device__ inline void plswap(int& a, int& b) {
    u32x2 r = __builtin_amdgcn_permlane32_swap((unsigned)a, (unsigned)b, false, false);
    a = (int)r[0];
    b = (int)r[1];
}

// ---------------------------------------------------------------------------
// Kernel 1 (unchanged, validated rounds 15-22): fragment-linear outputs
//   E1F [bc][nt64][c][r], E2F [bc][kt64][c][r], VTF [bc][kt64][d][o]
// ---------------------------------------------------------------------------
__global__ __launch_bounds__(256) void prep_kernel(
    const float* __restrict__ x,
    const float* __restrict__ W1, const float* __restrict__ b1,
    const float* __restrict__ W2, const float* __restrict__ b2,
    const float* __restrict__ W3,
    __bf16* __restrict__ e1f, __bf16* __restrict__ e2f, __bf16* __restrict__ vtf)
{
    const int t   = threadIdx.x;
    const int blk = blockIdx.x;
    const int bc  = blk >> 5, st = blk & 31;
    const long grow = (long)bc * NN + st * 64;
    const int w = t >> 6, l = t & 63, lg = l >> 4, li = l & 15;

    bf16x8 a[4][2];
    #pragma unroll
    for (int nb = 0; nb < 4; ++nb)
        #pragma unroll
        for (int kk = 0; kk < 2; ++kk) {
            const float* p = x + (grow + nb * 16 + li) * DD + kk * 32 + lg * 8;
            f32x4 v0 = *(const f32x4*)p, v1 = *(const f32x4*)(p + 4);
            #pragma unroll
            for (int j = 0; j < 4; ++j) {
                a[nb][kk][j]     = (__bf16)v0[j];
                a[nb][kk][4 + j] = (__bf16)v1[j];
            }
        }

    bf16x8 wf1[2], wf2[2], wf3[2];
    #pragma unroll
    for (int kk = 0; kk < 2; ++kk) {
        const float* p1 = W1 + (w * 16 + li) * DD + kk * 32 + lg * 8;
        const float* p2 = W2 + (w * 16 + li) * DD + kk * 32 + lg * 8;
        const float* p3 = W3 + (w * 16 + li) * DD + kk * 32 + lg * 8;
        f32x4 u0 = *(const f32x4*)p1, u1 = *(const f32x4*)(p1 + 4);
        f32x4 v0 = *(const f32x4*)p2, v1 = *(const f32x4*)(p2 + 4);
        f32x4 t0 = *(const f32x4*)p3, t1 = *(const f32x4*)(p3 + 4);
        #pragma unroll
        for (int j = 0; j < 4; ++j) {
            wf1[kk][j] = (__bf16)u0[j]; wf1[kk][4 + j] = (__bf16)u1[j];
            wf2[kk][j] = (__bf16)v0[j]; wf2[kk][4 + j] = (__bf16)v1[j];
            wf3[kk][j] = (__bf16)t0[j]; wf3[kk][4 + j] = (__bf16)t1[j];
        }
    }
    const f32x4 bq1 = *(const f32x4*)(b1 + w * 16 + lg * 4);
    const f32x4 bq2 = *(const f32x4*)(b2 + w * 16 + lg * 4);

    const size_t tbase = (size_t)(bc * 32 + st) * 4096;

    #pragma unroll
    for (int nb = 0; nb < 4; ++nb) {
        f32x4 acc1 = {0.f,0.f,0.f,0.f}, acc2 = {0.f,0.f,0.f,0.f}, acc3 = {0.f,0.f,0.f,0.f};
        #pragma unroll
        for (int kk = 0; kk < 2; ++kk) {
            acc1 = mfma16(wf1[kk], a[nb][kk], acc1);   // D[h][n]
            acc2 = mfma16(wf2[kk], a[nb][kk], acc2);   // D[h][n]
            acc3 = mfma16(a[nb][kk], wf3[kk], acc3);   // D[n][o]
        }
        bf16x4 q1, q2, q3;
        #pragma unroll
        for (int r = 0; r < 4; ++r) {
            q1[r] = (__bf16)(acc1[r] + bq1[r]);
            q2[r] = (__bf16)(acc2[r] + bq2[r]);
            q3[r] = (__bf16)acc3[r];
        }
        *(bf16x4*)&e1f[tbase + (w * 2 + (lg >> 1)) * 512 + (nb * 16 + li) * 8 + (lg & 1) * 4] = q1;
        *(bf16x4*)&e2f[tbase + (w * 2 + (lg >> 1)) * 512 + (nb * 16 + li) * 8 + (lg & 1) * 4] = q2;
        *(bf16x4*)&vtf[tbase + (nb * 2 + (lg >> 1)) * 512 + (w * 16 + li) * 8 + (lg & 1) * 4] = q3;
    }
}

// ---------------------------------------------------------------------------
// Kernel 2 v12: round-18 base + T15 pipeline: each half-iteration runs
// S(kt) [MFMA] in parallel with packQ+swap(kt-1) [VALU] + PV(kt-1) [MFMA]
// (prev-tile finish is dependency-independent of cur-tile S -> pipe-diverse
// scheduling window). ef(kt+1) issued at head of half (700cyc slack);
// vf(kt+1) after the PV that frees its buffer. Tile order/lockstep unchanged.
// ---------------------------------------------------------------------------
__global__ __launch_bounds__(128, 2) void fused_kernel(
    const __bf16* __restrict__ e1f, const __bf16* __restrict__ e2f,
    const __bf16* __restrict__ vtf, const float* __restrict__ b3,
    float* __restrict__ out)
{
    __shared__ float scratch[4096];      // epilogue m-half combine (16KB)

    const int t   = threadIdx.x;
    const int bid = blockIdx.x;
    const int x8 = bid & 7, jj = bid >> 3;          // jj in 0..127
    const int bc = x8 * 4 + (jj & 3), nt = jj >> 2;

    const int wm = t >> 6, l = t & 63;
    const int l31 = l & 31, hi5 = l >> 5;
    const int nbase = nt * 64;

    const float bv0 = b3[l31], bv1 = b3[32 + l31];

    bf16x8 e1v[2][4];
    #pragma unroll
    for (int nb = 0; nb < 2; ++nb) {
        const __bf16* p = e1f + ((size_t)bc * 32 + nt) * 4096 + hi5 * 512 + (nb * 32 + l31) * 8;
        #pragma unroll
        for (int kk = 0; kk < 4; ++kk)
            e1v[nb][kk] = *(const bf16x8*)(p + kk * 1024);
    }

    f32x16 fz;
    #pragma unroll
    for (int i = 0; i < 16; ++i) fz[i] = 0.f;
    f32x16 hacc[2][2];   // [nb][fb]
    #pragma unroll
    for (int nb = 0; nb < 2; ++nb)
        #pragma unroll
        for (int fb = 0; fb < 2; ++fb)
            #pragma unroll
            for (int i = 0; i < 16; ++i) hacc[nb][fb][i] = 0.f;

    const __bf16* E2 = e2f + (size_t)bc * 131072 + hi5 * 512 + (wm * 32 + l31) * 8;
    const __bf16* VT = vtf + (size_t)bc * 131072 + (wm * 4 + hi5) * 512 + l31 * 8;

    auto loadEF = [&](int kt, bf16x8 (&ef)[4]) {
        const __bf16* p = E2 + (size_t)kt * 4096;
        #pragma unroll
        for (int kk = 0; kk < 4; ++kk)
            ef[kk] = *(const bf16x8*)(p + kk * 1024);
    };
    auto loadVF = [&](int kt, bf16x8 (&vf)[4]) {
        const __bf16* p = VT + (size_t)kt * 4096;
        #pragma unroll
        for (int kk2 = 0; kk2 < 2; ++kk2) {
            vf[kk2 * 2 + 0] = *(const bf16x8*)(p + kk2 * 1024);
            vf[kk2 * 2 + 1] = *(const bf16x8*)(p + kk2 * 1024 + 256);
        }
    };
    auto computeS = [&](bf16x8 (&ef)[4], f32x16 (&sT)[2]) {
        sT[0] = mfma32(ef[0], e1v[0][0], fz);
        sT[1] = mfma32(ef[0], e1v[1][0], fz);
        #pragma unroll
        for (int kk = 1; kk < 4; ++kk) {
            sT[0] = mfma32(ef[kk], e1v[0][kk], sT[0]);
            sT[1] = mfma32(ef[kk], e1v[1][kk], sT[1]);
        }
    };
    auto packQ = [&](const f32x16 (&sT)[2], i32x2 (&Q)[2][4]) {
        #pragma unroll
        for (int nb = 0; nb < 2; ++nb)
            #pragma unroll
            for (int g = 0; g < 4; ++g) {
                bf16x4 q0;
                #pragma unroll
                for (int r = 0; r < 4; ++r)
                    q0[r] = (__bf16)fmaxf(sT[nb][4 * g + r], 0.f);
                Q[nb][g] = __builtin_bit_cast(i32x2, q0);
            }
    };
    auto doPV = [&](i32x2 (&Q)[2][4], bf16x8 (&vf)[4]) {
        #pragma unroll
        for (int kk2 = 0; kk2 < 2; ++kk2)
            #pragma unroll
            for (int nb = 0; nb < 2; ++nb) {
                int a0 = Q[nb][2 * kk2][0],     a1 = Q[nb][2 * kk2][1];
                int b0 = Q[nb][2 * kk2 + 1][0], b1 = Q[nb][2 * kk2 + 1][1];
                plswap(a0, b0);
                plswap(a1, b1);
                i32x4 pfi = { a0, a1, b0, b1 };
                bf16x8 pf = __builtin_bit_cast(bf16x8, pfi);
                hacc[nb][0] = mfma32(pf, vf[kk2 * 2 + 0], hacc[nb][0]);
                hacc[nb][1] = mfma32(pf, vf[kk2 * 2 + 1], hacc[nb][1]);
            }
    };

    bf16x8 efA[4], vfA[4], efB[4], vfB[4];
    f32x16 sTA[2], sTB[2];
    i32x2 Q[2][4];

    // prologue: tiles 0 (A) and 1 (B) loaded; S(0) computed
    loadEF(0, efA); loadVF(0, vfA);
    loadEF(1, efB); loadVF(1, vfB);
    computeS(efA, sTA);

    for (int j = 0; j < 15; ++j) {
        // half1: S(2j+1) || finish(2j).  ef(2j+2) issued at head.
        loadEF(2 * j + 2, efA);
        computeS(efB, sTB);      // MFMA, tile 2j+1
        packQ(sTA, Q);           // VALU, tile 2j  (independent of S above)
        doPV(Q, vfA);            // MFMA, tile 2j
        loadVF(2 * j + 2, vfA);  // vfA free after PV read

        // half2: S(2j+2) || finish(2j+1).
        loadEF(2 * j + 3, efB);
        computeS(efA, sTA);      // MFMA, tile 2j+2
        packQ(sTB, Q);           // VALU, tile 2j+1
        doPV(Q, vfB);            // MFMA, tile 2j+1
        loadVF(2 * j + 3, vfB);
    }

    // epilogue: finish tile 30, then S+finish tile 31
    packQ(sTA, Q);
    doPV(Q, vfA);
    computeS(efB, sTB);
    packQ(sTB, Q);
    doPV(Q, vfB);

    // ---- epilogue: combine m-halves via LDS, add b3, store fp32 ----
    if (wm == 1) {
        #pragma unroll
        for (int nb = 0; nb < 2; ++nb)
            #pragma unroll
            for (int q = 0; q < 8; ++q) {
                f32x4 v;
                #pragma unroll
                for (int r = 0; r < 4; ++r) {
                    const int idx = q * 4 + r;          // 0..31
                    v[r] = hacc[nb][idx >> 4][idx & 15];
                }
                *(f32x4*)&scratch[nb * 2048 + q * 256 + l * 4] = v;
            }
    }
    __syncthreads();
    if (wm == 0) {
        #pragma unroll
        for (int nb = 0; nb < 2; ++nb)
            #pragma unroll
            for (int q = 0; q < 8; ++q) {
                f32x4 v = *(const f32x4*)&scratch[nb * 2048 + q * 256 + l * 4];
                #pragma unroll
                for (int r = 0; r < 4; ++r) {
                    const int idx = q * 4 + r;
                    hacc[nb][idx >> 4][idx & 15] += v[r];
                }
            }
        #pragma unroll
        for (int nb = 0; nb < 2; ++nb) {
            const size_t ob = ((size_t)bc * NN + nbase + nb * 32) * DD;
            #pragma unroll
            for (int reg = 0; reg < 16; ++reg) {
                const int n = (reg & 3) + 8 * (reg >> 2) + 4 * hi5;
                out[ob + (size_t)n * DD + l31]      = hacc[nb][0][reg] + bv0;
                out[ob + (size_t)n * DD + 32 + l31] = hacc[nb][1][reg] + bv1;
            }
        }
    }
}

extern "C" void kernel_launch(void* const* d_in, const int* in_sizes, int n_in,
                              void* d_out, int out_size, void* d_ws, size_t ws_size,
                              hipStream_t stream) {
    const float* x  = (const float*)d_in[0];
    const float* W1 = (const float*)d_in[1];
    const float* b1 = (const float*)d_in[2];
    const float* W2 = (const float*)d_in[3];
    const float* b2 = (const float*)d_in[4];
    const float* W3 = (const float*)d_in[5];
    const float* b3 = (const float*)d_in[6];
    float* out = (float*)d_out;

    __bf16* e1f = (__bf16*)d_ws;                      // 8 MB fragment-linear
    __bf16* e2f = e1f + (size_t)BCH * NN * DD;        // 8 MB fragment-linear
    __bf16* vtf = e2f + (size_t)BCH * NN * DD;        // 8 MB fragment-linear

    prep_kernel<<<dim3(1024), dim3(256), 0, stream>>>(x, W1, b1, W2, b2, W3, e1f, e2f, vtf);
    fused_kernel<<<dim3(1024), dim3(128), 0, stream>>>(e1f, e2f, vtf, b3, out);
}